// Round 3
// baseline (293.924 us; speedup 1.0000x reference)
//
#include <hip/hip_runtime.h>

typedef __attribute__((ext_vector_type(8))) short bfrag;   // 8 bf16 (4 VGPRs) MFMA operand
typedef __attribute__((ext_vector_type(4))) short s4;      // 4 bf16 (2 VGPRs) 16x16x16 operand
typedef __attribute__((ext_vector_type(4))) float f4;      // MFMA accumulator
typedef unsigned short u16;
typedef __attribute__((ext_vector_type(4))) unsigned short u16x4;

#define L2T 0.20762050593046f   // log2(10000)/64

__device__ inline u16 f2bf(float x) {
    unsigned u = __builtin_bit_cast(unsigned, x);
    u += 0x7FFFu + ((u >> 16) & 1u);   // round-to-nearest-even
    return (u16)(u >> 16);
}

__device__ inline void gload16(const u16* g, u16* l) {
    // async global->LDS, 16B/lane; LDS dst = wave-uniform base + lane*16
    __builtin_amdgcn_global_load_lds((const __attribute__((address_space(1))) u16*)g,
                                     (__attribute__((address_space(3))) u16*)l, 16, 0, 0);
}

// ---------------- fused prep: cast X/wq/wk/wv/wo -> bf16, concat biases ----------------
__global__ __launch_bounds__(256) void prep(const float* __restrict__ X,  const float* __restrict__ wq,
                                            const float* __restrict__ wk, const float* __restrict__ wv,
                                            const float* __restrict__ wo, const float* __restrict__ bq,
                                            const float* __restrict__ bk, const float* __restrict__ bv,
                                            u16* __restrict__ Xb, u16* __restrict__ Wqkv,
                                            u16* __restrict__ Wo_, float* __restrict__ biasqkv) {
    const int v = blockIdx.x * 256 + threadIdx.x;
    const float* src; u16* dst; int idx;
    if (v < 1048576)      { src = X;  dst = Xb;              idx = v; }
    else if (v < 2097152) { src = wq; dst = Wqkv;            idx = v - 1048576; }
    else if (v < 2359296) { src = wk; dst = Wqkv + 4194304;  idx = v - 2097152; }
    else if (v < 2621440) { src = wv; dst = Wqkv + 5242880;  idx = v - 2359296; }
    else if (v < 3670016) { src = wo; dst = Wo_;             idx = v - 2621440; }
    else {
        const int b = v - 3670016;   // 768 float4 = 3072 bias floats
        const float* s = (b < 512) ? (bq + b * 4) : (b < 640) ? (bk + (b - 512) * 4) : (bv + (b - 640) * 4);
        *(float4*)(biasqkv + b * 4) = *(const float4*)s;
        return;
    }
    float4 t = *(const float4*)(src + (size_t)idx * 4);
    u16x4 o;
    o.x = f2bf(t.x); o.y = f2bf(t.y); o.z = f2bf(t.z); o.w = f2bf(t.w);
    *(u16x4*)(dst + (size_t)idx * 4) = o;
}

// ---------------- fused QKV GEMM + bias + RoPE + repack ----------------
// C = Xb[2048][2048] * Wqkv[3072][2048]^T. 128x128 tiles, BK=32, 256 thr = 4 waves;
// wave w owns rows w*32..w*32+31 x all 128 cols (acc[2][8]) so RoPE partners
// (i, i+64) are acc[i][j] <-> acc[i][j+4] IN-LANE. tn: 0..15 Q head tn,
// 16..19 K head tn-16, 20..23 V kv-head tn-20 (written transposed to Vt).
__global__ __launch_bounds__(256) void gemm_qkv_rope(const u16* __restrict__ A, const u16* __restrict__ B,
                                                     const float* __restrict__ bias,
                                                     u16* __restrict__ Qr, u16* __restrict__ Kr,
                                                     u16* __restrict__ Vt) {
    const int K = 2048;
    __shared__ u16 As[128 * 32];
    __shared__ u16 Bs[128 * 32];
    const int tm = blockIdx.y, tn = blockIdx.x;
    const int tid = threadIdx.x;
    const int w = tid >> 6, lane = tid & 63, quad = lane >> 4, l16 = lane & 15;

    f4 acc[2][8];
#pragma unroll
    for (int i = 0; i < 2; i++)
#pragma unroll
        for (int j = 0; j < 8; j++) acc[i][j] = f4{0.f, 0.f, 0.f, 0.f};

    const int srow = w * 32 + (lane >> 2);
    const int scol = (lane & 3) * 8;
    const u16* aPtr = A + (size_t)(tm * 128 + srow) * K + scol;
    const u16* bPtr = B + (size_t)(tn * 128 + srow) * K + scol;
    u16* aLds0 = &As[(w * 32) * 32];
    u16* aLds1 = &As[(w * 32 + 16) * 32];
    u16* bLds0 = &Bs[(w * 32) * 32];
    u16* bLds1 = &Bs[(w * 32 + 16) * 32];
    const size_t rowskip = (size_t)16 * K;

    for (int k0 = 0; k0 < K; k0 += 32) {
        __syncthreads();
        gload16(aPtr,           aLds0);
        gload16(aPtr + rowskip, aLds1);
        gload16(bPtr,           bLds0);
        gload16(bPtr + rowskip, bLds1);
        aPtr += 32; bPtr += 32;
        __syncthreads();

        bfrag af[2], bf[8];
#pragma unroll
        for (int i = 0; i < 2; i++)
            af[i] = *(const bfrag*)(&As[(w * 32 + i * 16 + l16) * 32 + quad * 8]);
#pragma unroll
        for (int j = 0; j < 8; j++)
            bf[j] = *(const bfrag*)(&Bs[(j * 16 + l16) * 32 + quad * 8]);
#pragma unroll
        for (int i = 0; i < 2; i++)
#pragma unroll
            for (int j = 0; j < 8; j++)
                acc[i][j] = __builtin_amdgcn_mfma_f32_16x16x32_bf16(af[i], bf[j], acc[i][j], 0, 0, 0);
    }

    // ---- epilogue ----
    if (tn < 20) {   // Q or K: bias + RoPE + head-major write
        const int qk = (tn < 16);
        const int hd = qk ? tn : (tn - 16);
        u16* base = qk ? (Qr + (size_t)hd * 2048 * 128) : (Kr + (size_t)hd * 2048 * 128);
        float bia0[4], bia1[4], inv[4];
#pragma unroll
        for (int j = 0; j < 4; j++) {
            const int ip = j * 16 + l16;
            bia0[j] = bias[tn * 128 + ip];
            bia1[j] = bias[tn * 128 + ip + 64];
            inv[j] = exp2f(-(float)ip * L2T);
        }
#pragma unroll
        for (int i = 0; i < 2; i++) {
            const int s0 = tm * 128 + w * 32 + i * 16 + quad * 4;
#pragma unroll
            for (int r = 0; r < 4; r++) {
                const int s = s0 + r;
                const float fs = (float)s;
                u16* rowp = base + (size_t)s * 128;
#pragma unroll
                for (int j = 0; j < 4; j++) {
                    const int ip = j * 16 + l16;
                    float sn, cs;
                    __sincosf(fs * inv[j], &sn, &cs);
                    const float a0 = acc[i][j][r] + bia0[j];
                    const float a1 = acc[i][j + 4][r] + bia1[j];
                    rowp[ip]      = f2bf(a0 * cs - a1 * sn);
                    rowp[ip + 64] = f2bf(a1 * cs + a0 * sn);
                }
            }
        }
    } else {         // V: bias + transposed write to Vt[4][128][2048]
        const int kvh = tn - 20;
#pragma unroll
        for (int j = 0; j < 8; j++) {
            const int d = j * 16 + l16;
            const float bv = bias[tn * 128 + d];
            u16* base = Vt + ((size_t)(kvh * 128 + d)) * 2048;
#pragma unroll
            for (int i = 0; i < 2; i++) {
                const int s0 = tm * 128 + w * 32 + i * 16 + quad * 4;
                u16x4 o;
#pragma unroll
                for (int r = 0; r < 4; r++) o[r] = f2bf(acc[i][j][r] + bv);
                *(u16x4*)(base + s0) = o;
            }
        }
    }
}

// ---------------- GEMM: C[M][N] = A[M][K](bf16) * B[N][K]^T(bf16), fp32 out ----------------
// 128x128 tile, BK=32, 256 threads = 4 waves (2x2), m97 structure, global_load_lds staging.
__global__ __launch_bounds__(256) void gemm_bt(const u16* __restrict__ A, const u16* __restrict__ B,
                                               float* __restrict__ C, int M, int N, int K) {
    __shared__ u16 As[128 * 32];
    __shared__ u16 Bs[128 * 32];
    const int tm = blockIdx.y, tn = blockIdx.x;
    const int tid = threadIdx.x;
    const int w = tid >> 6, lane = tid & 63, quad = lane >> 4, l16 = lane & 15;
    const int wm = w >> 1, wn = w & 1;

    f4 acc[4][4];
#pragma unroll
    for (int i = 0; i < 4; i++)
#pragma unroll
        for (int j = 0; j < 4; j++) acc[i][j] = f4{0.f, 0.f, 0.f, 0.f};

    const int srow = w * 32 + (lane >> 2);
    const int scol = (lane & 3) * 8;
    const u16* aPtr = A + (size_t)(tm * 128 + srow) * K + scol;
    const u16* bPtr = B + (size_t)(tn * 128 + srow) * K + scol;
    u16* aLds0 = &As[(w * 32) * 32];
    u16* aLds1 = &As[(w * 32 + 16) * 32];
    u16* bLds0 = &Bs[(w * 32) * 32];
    u16* bLds1 = &Bs[(w * 32 + 16) * 32];
    const size_t rowskip = (size_t)16 * K;

    for (int k0 = 0; k0 < K; k0 += 32) {
        __syncthreads();
        gload16(aPtr,           aLds0);
        gload16(aPtr + rowskip, aLds1);
        gload16(bPtr,           bLds0);
        gload16(bPtr + rowskip, bLds1);
        aPtr += 32; bPtr += 32;
        __syncthreads();

        bfrag af[4], bf[4];
#pragma unroll
        for (int i = 0; i < 4; i++)
            af[i] = *(const bfrag*)(&As[(wm * 64 + i * 16 + l16) * 32 + quad * 8]);
#pragma unroll
        for (int j = 0; j < 4; j++)
            bf[j] = *(const bfrag*)(&Bs[(wn * 64 + j * 16 + l16) * 32 + quad * 8]);
#pragma unroll
        for (int i = 0; i < 4; i++)
#pragma unroll
            for (int j = 0; j < 4; j++)
                acc[i][j] = __builtin_amdgcn_mfma_f32_16x16x32_bf16(af[i], bf[j], acc[i][j], 0, 0, 0);
    }

#pragma unroll
    for (int i = 0; i < 4; i++) {
#pragma unroll
        for (int j = 0; j < 4; j++) {
            const int col = tn * 128 + wn * 64 + j * 16 + l16;
#pragma unroll
            for (int r = 0; r < 4; r++) {
                const int row = tm * 128 + wm * 64 + i * 16 + quad * 4 + r;
                C[(size_t)row * N + col] = acc[i][j][r];
            }
        }
    }
}

// ---------------- flash attention (causal), S^T formulation, 128-key tiles ----------------
// 512 blocks x 256 threads = 4 waves, 64KB LDS -> 2 blocks/CU, 8 waves/CU (the implicit
// inter-block pipeline). Each wave = q-head kv*4+w over THIRTY-TWO q rows (2 MFMA
// row-groups): K/V fragments are ds_read ONCE and feed BOTH groups' MFMAs -> LDS bytes
// per unit work halved vs 16-row waves.
// Balance: block = (kv, G in [0,64), split sp in {0,1}); processes key tiles kt = sp,
// sp+2, ... < ktn(G) = G/4+1. Streaming softmax has no running max, so key-split partials
// are purely additive: block writes unnormalized f32 O-partials + f32 row-sum partials to
// its split's buffer; combine() sums, normalizes, casts. Block order makes BOTH plausible
// CU pairings -- contiguous (2i,2i+1) and round-robin (b,b+256) -- heavy+light
// complementary (~8.5 tiles/CU).
// S^T via swapped-operand 16x16x32 MFMA: lane holds P[q=l16][key=quad*4+r] which IS the
// 16x16x16 MFMA B layout, so PV runs as mfma_f32_16x16x16bf16_1k with no P round-trip.
// PV C/D layout: oacc[g][ct][r] = O[q = G*32+g*16+l16][d = ct*16+quad*4+r] (f4 walks d!).
__global__ __launch_bounds__(256, 2) void flash_attn(const u16* __restrict__ Qr, const u16* __restrict__ Kr,
                                                     const u16* __restrict__ Vt,
                                                     float* __restrict__ opA, float* __restrict__ opB,
                                                     float* __restrict__ psA, float* __restrict__ psB) {
    const int bid = blockIdx.x;
    const int i128 = (bid >> 1) & 127;
    const int kv = i128 & 3;
    const int p = i128 >> 2;          // 0..31
    const int sp = bid & 1;           // key-tile parity split
    const int hi = bid >> 8;
    const int G = (sp ^ hi) ? p : (63 - p);   // 32-row q-block index, 0..63
    const int tid = threadIdx.x;
    const int w = tid >> 6, lane = tid & 63, quad = lane >> 4, l16 = lane & 15;
    const int h = kv * 4 + w;         // wave's q-head

    __shared__ u16 ks[128 * 128];     // K tile [128 keys][128 d], swizzled 16B chunks
    __shared__ u16 vt[128 * 128];     // V^T tile [128 d][128 keys], swizzled 16B chunks

    const u16* kbase = Kr + (size_t)kv * 2048 * 128;
    const u16* vbase = Vt + (size_t)kv * 128 * 2048;
    const float C = 0.08838834764831845f * 1.4426950408889634f;  // (1/sqrt(128))*log2(e)

    // Q fragments for both row-groups (B-operand layout: rows q=l16, k at quad*8)
    bfrag aq[2][4];
    const u16* qbase = Qr + ((size_t)(h * 2048 + G * 32 + l16)) * 128 + quad * 8;
#pragma unroll
    for (int kb = 0; kb < 4; kb++) {
        aq[0][kb] = *(const bfrag*)(qbase + kb * 32);
        aq[1][kb] = *(const bfrag*)(qbase + 16 * 128 + kb * 32);
    }

    f4 oacc[2][8];
#pragma unroll
    for (int g = 0; g < 2; g++)
#pragma unroll
        for (int ct = 0; ct < 8; ct++) oacc[g][ct] = f4{0.f, 0.f, 0.f, 0.f};
    float psum0 = 0.f, psum1 = 0.f;   // per-lane partial row-sums (q = l16 of each group)

    const int qg0 = G * 32 + l16;     // group-0 lane q row; group 1 = +16
    const int ktn = G / 4 + 1;        // causal 128-key tiles for rows [G*32, G*32+32)
    const int lastkt = ktn - 1;       // only this tile needs the causal mask

    for (int kt = sp; kt < ktn; kt += 2) {
        __syncthreads();
        // stage K [128][128]: 2048 chunks of 16B, 8 per thread
#pragma unroll
        for (int i = 0; i < 8; i++) {
            const int ci = (w * 8 + i) * 64 + lane;
            const int r = ci >> 4, c = (ci & 15) ^ (r & 15);
            gload16(kbase + (size_t)(kt * 128 + r) * 128 + c * 8, &ks[(w * 8 + i) * 512]);
        }
        // stage V^T [128 d][128 keys]: 2048 chunks
#pragma unroll
        for (int i = 0; i < 8; i++) {
            const int ci = (w * 8 + i) * 64 + lane;
            const int r = ci >> 4, c = (ci & 15) ^ (r & 15);
            gload16(vbase + (size_t)r * 2048 + kt * 128 + c * 8, &vt[(w * 8 + i) * 512]);
        }
        __syncthreads();

        // S^T + streaming softmax, fused per 16-key slab; K-frag read once feeds BOTH groups
        s4 pa[2][8];
#pragma unroll
        for (int nt = 0; nt < 8; nt++) {
            f4 c0 = f4{0.f, 0.f, 0.f, 0.f}, c1 = f4{0.f, 0.f, 0.f, 0.f};
#pragma unroll
            for (int kb = 0; kb < 4; kb++) {
                bfrag a = *(const bfrag*)(&ks[((nt * 16 + l16) * 16 + ((quad + kb * 4) ^ l16)) * 8]);
                c0 = __builtin_amdgcn_mfma_f32_16x16x32_bf16(a, aq[0][kb], c0, 0, 0, 0);
                c1 = __builtin_amdgcn_mfma_f32_16x16x32_bf16(a, aq[1][kb], c1, 0, 0, 0);
            }
            if (kt == lastkt) {
                const int key = kt * 128 + nt * 16 + quad * 4;
#pragma unroll
                for (int r = 0; r < 4; r++) {
                    if (key + r > qg0)      c0[r] = -INFINITY;
                    if (key + r > qg0 + 16) c1[r] = -INFINITY;
                }
            }
#pragma unroll
            for (int r = 0; r < 4; r++) {
                const float p0 = exp2f(fminf(c0[r] * C, 40.f));
                const float p1 = exp2f(fminf(c1[r] * C, 40.f));
                psum0 += p0; psum1 += p1;
                pa[0][nt][r] = (short)f2bf(p0);
                pa[1][nt][r] = (short)f2bf(p1);
            }
        }

        // O[q][d] += P*V via 16x16x16: V^T frag read once feeds BOTH groups
#pragma unroll
        for (int nt = 0; nt < 8; nt++) {
#pragma unroll
            for (int ct = 0; ct < 8; ct++) {
                const int d = ct * 16 + l16;
                s4 a = *(const s4*)(&vt[(d * 16 + ((nt * 2 + (quad >> 1)) ^ l16)) * 8 + (quad & 1) * 4]);
                oacc[0][ct] = __builtin_amdgcn_mfma_f32_16x16x16bf16_1k(a, pa[0][nt], oacc[0][ct], 0, 0, 0);
                oacc[1][ct] = __builtin_amdgcn_mfma_f32_16x16x16bf16_1k(a, pa[1][nt], oacc[1][ct], 0, 0, 0);
            }
        }
    }

    // epilogue: per group, reduce psum over the 4 quads sharing q=l16, then write f32
    // partials: opart layout (f4 units) [h][qg16][ct][quad][l16]; each f4 holds d =
    // ct*16+quad*4 .. +3 at fixed q = qg16*16+l16. psum partial [h][q]. Zero-tile blocks
    // (ktn<=sp) naturally write zeros (additive identity).
    float* opp = sp ? opB : opA;
    float* psp = sp ? psB : psA;
#pragma unroll
    for (int g = 0; g < 2; g++) {
        float s = g ? psum1 : psum0;
        s += __shfl_xor(s, 16, 64);
        s += __shfl_xor(s, 32, 64);
        if (quad == 0) psp[h * 2048 + G * 32 + g * 16 + l16] = s;
        const int qg16 = G * 2 + g;
#pragma unroll
        for (int ct = 0; ct < 8; ct++) {
            const size_t idx = ((((size_t)h * 128 + qg16) * 8 + ct) * 4 + quad) * 16 + l16;
            *(f4*)(opp + idx * 4) = oacc[g][ct];
        }
    }
}

// ---------------- combine: attnout = bf16( (opA+opB) / (psA+psB) ) ----------------
// 262144 threads; thread t = (h, qg16, ct, l16) gathers its row's 4 quads (4 coalesced f4
// loads per partial: consecutive l16 -> consecutive 16B units), one scalar denominator at
// q = qg16*16+l16, and stores 16 contiguous bf16 (32B) at attnout[q][h*128 + ct*16 ..+15].
// f4 component r maps to d = ct*16 + quad*4 + r (PV C/D layout: f4 walks d, NOT q).
__global__ __launch_bounds__(256) void combine(const float* __restrict__ opA, const float* __restrict__ opB,
                                               const float* __restrict__ psA, const float* __restrict__ psB,
                                               u16* __restrict__ attnout) {
    const size_t t = (size_t)blockIdx.x * 256 + threadIdx.x;   // 0 .. 262143
    const int l16 = (int)t & 15;
    const int ct = (int)(t >> 4) & 7;
    const int qg16 = (int)(t >> 7) & 127;
    const int h = (int)(t >> 14);
    const int q = qg16 * 16 + l16;
    // float offset of (h, qg16, ct, quad=0, l16): idx*4 with idx = (((h*128+qg16)*8+ct)*4+0)*16+l16
    const size_t base = ((((size_t)h * 128 + qg16) * 8 + ct) * 256) + (size_t)l16 * 4;

    const float inv = 1.0f / (psA[h * 2048 + q] + psB[h * 2048 + q]);

    u16x4 ov[4];
#pragma unroll
    for (int quad = 0; quad < 4; quad++) {
        const f4 oa = *(const f4*)(opA + base + quad * 64);
        const f4 ob = *(const f4*)(opB + base + quad * 64);
#pragma unroll
        for (int r = 0; r < 4; r++) ov[quad][r] = f2bf((oa[r] + ob[r]) * inv);
    }
    u16* dst = attnout + (size_t)q * 2048 + h * 128 + ct * 16;
    *(u16x4*)(dst)      = ov[0];
    *(u16x4*)(dst + 4)  = ov[1];
    *(u16x4*)(dst + 8)  = ov[2];
    *(u16x4*)(dst + 12) = ov[3];
}

// ---------------- launch ----------------
extern "C" void kernel_launch(void* const* d_in, const int* in_sizes, int n_in,
                              void* d_out, int out_size, void* d_ws, size_t ws_size,
                              hipStream_t stream) {
    const float* X  = (const float*)d_in[0];
    const float* wq = (const float*)d_in[3];
    const float* bq = (const float*)d_in[4];
    const float* wk = (const float*)d_in[5];
    const float* bk = (const float*)d_in[6];
    const float* wv = (const float*)d_in[7];
    const float* bv = (const float*)d_in[8];
    const float* wo = (const float*)d_in[9];

    char* ws = (char*)d_ws;
    u16*   Xb      = (u16*)(ws);                         // 8 MB  (dead after gemm_qkv_rope)
    u16*   Wqkv    = (u16*)(ws + 8388608);               // 12 MB (dead after gemm_qkv_rope)
    u16*   Wo      = (u16*)(ws + 20971520);              // 8 MB  (live until gemm_bt)
    float* biasqkv = (float*)(ws + 29360128);            // 12 KB (ends 29372416)
    u16*   Qr      = (u16*)(ws + 54538240);              // 8 MB   [16][2048][128]
    u16*   Kr      = (u16*)(ws + 62926848);              // 2 MB   [4][2048][128]
    u16*   attnout = (u16*)(ws + 67121152);              // 8 MB   [2048][2048]
    u16*   Vt      = (u16*)(ws + 75509760);              // 2 MB   [4][128][2048]
    // flash partials reuse dead/gap regions (no footprint growth past 79.7 MB):
    float* opA     = (float*)(ws);                       // 16 MB over Xb+Wqkv (dead)
    float* opB     = (float*)(ws + 29372416);            // 16 MB in the 29.37..54.5 MB gap
    float* psA     = (float*)(ws + 46149632);            // 128 KB
    float* psB     = (float*)(ws + 46280704);            // 128 KB (ends 46.4 MB < 54.5 MB)

    prep<<<14339, 256, 0, stream>>>(X, wq, wk, wv, wo, bq, bk, bv, Xb, Wqkv, Wo, biasqkv);
    gemm_qkv_rope<<<dim3(24, 16), 256, 0, stream>>>(Xb, Wqkv, biasqkv, Qr, Kr, Vt);
    flash_attn<<<512, 256, 0, stream>>>(Qr, Kr, Vt, opA, opB, psA, psB);
    combine<<<1024, 256, 0, stream>>>(opA, opB, psA, psB, attnout);
    gemm_bt<<<dim3(16, 16), 256, 0, stream>>>(attnout, Wo, (float*)d_out, 2048, 2048, 2048);
}